// Round 9
// baseline (152.180 us; speedup 1.0000x reference)
//
#include <hip/hip_runtime.h>

#define NB 256
#define NJ 24
#define NV 6890
#define WT_LD 7168   // transposed-W row stride (floats); covers max OOB tail read

// ---------------------------------------------------------------------------
// Kernel 0: transpose weights (V,J) -> (J, WT_LD) in d_ws, coalesced both sides.
// ---------------------------------------------------------------------------
__global__ __launch_bounds__(256) void transpose_w2(const float* __restrict__ w,
                                                    float* __restrict__ wT) {
    __shared__ float Wl[256 * 25];   // row stride 25: gcd(25,32)=1
    const int v0 = blockIdx.x * 256, tid = threadIdx.x;
    const int nvalid = min(256, NV - v0);

    const float4* wg = reinterpret_cast<const float4*>(w + (size_t)v0 * NJ);
    const int nf4 = nvalid * NJ / 4;
    for (int i = tid; i < nf4; i += 256) {
        const float4 q = wg[i];
        const int f = i * 4, v = f / NJ, j = f % NJ;   // j in {0,4,...,20}
        float* d = &Wl[v * 25 + j];
        d[0] = q.x; d[1] = q.y; d[2] = q.z; d[3] = q.w;
    }
    __syncthreads();

#pragma unroll
    for (int j = 0; j < NJ; ++j)
        for (int v = tid; v < nvalid; v += 256)
            wT[(size_t)j * WT_LD + v0 + v] = Wl[v * 25 + j];   // coalesced store
}

// ---------------------------------------------------------------------------
// Kernel 1: kinematic chain via parallel ancestor doubling (unchanged, passing).
// ---------------------------------------------------------------------------
__device__ __constant__ int ANC[4][NJ] = {
  {-1, 0, 0, 0, 1, 2, 3, 4, 5, 6, 7, 8, 9, 9, 9,12,13,14,16,17,18,19,20,21},
  {-1,-1,-1,-1, 0, 0, 0, 1, 2, 3, 4, 5, 6, 6, 6, 9, 9, 9,13,14,16,17,18,19},
  {-1,-1,-1,-1,-1,-1,-1,-1,-1,-1, 0, 0, 0, 0, 0, 3, 3, 3, 6, 6, 9, 9,13,14},
  {-1,-1,-1,-1,-1,-1,-1,-1,-1,-1,-1,-1,-1,-1,-1,-1,-1,-1,-1,-1,-1,-1, 0, 0}};

__global__ __launch_bounds__(288) void chain2(
    const float* __restrict__ rot,      // (B,J,3,3)
    const float* __restrict__ joints,   // (B,J,3)
    float* __restrict__ posed_joints,   // (B,J,3)
    float* __restrict__ rel_tf)         // (B,J,4,4)
{
    __shared__ float Jl[NJ * 3];
    __shared__ float MA[NJ * 12];
    __shared__ float MB[NJ * 12];
    const int b = blockIdx.x, tid = threadIdx.x;
    const int j = tid / 12, e = tid % 12, r = e >> 2, c = e & 3;
    constexpr int par[NJ] = {0,0,0,0,1,2,3,4,5,6,7,8,9,9,9,12,13,14,16,17,18,19,20,21};

    if (tid < NJ * 3) Jl[tid] = joints[(size_t)b * NJ * 3 + tid];
    __syncthreads();

    float tv;
    if (c < 3) {
        tv = rot[(size_t)b * NJ * 9 + j * 9 + r * 3 + c];
    } else {
        tv = Jl[j * 3 + r];
        if (j > 0) tv -= Jl[par[j] * 3 + r];
    }
    MA[j * 12 + e] = tv;
    __syncthreads();

#define DSTEP(SRC, DST, K)                                                 \
    do {                                                                   \
        const int a = ANC[K][j];                                           \
        float nv;                                                          \
        if (a < 0) {                                                       \
            nv = SRC[j * 12 + e];                                          \
        } else {                                                           \
            nv = SRC[a * 12 + r * 4 + 0] * SRC[j * 12 + 0 + c]            \
               + SRC[a * 12 + r * 4 + 1] * SRC[j * 12 + 4 + c]            \
               + SRC[a * 12 + r * 4 + 2] * SRC[j * 12 + 8 + c];           \
            if (c == 3) nv += SRC[a * 12 + r * 4 + 3];                    \
        }                                                                  \
        DST[j * 12 + e] = nv;                                              \
        __syncthreads();                                                   \
    } while (0)

    DSTEP(MA, MB, 0);
    DSTEP(MB, MA, 1);
    DSTEP(MA, MB, 2);
    DSTEP(MB, MA, 3);

    const float aje = MA[j * 12 + e];
    if (c == 3) {
        posed_joints[(size_t)b * NJ * 3 + j * 3 + r] = aje;
        const float tj = MA[j * 12 + r * 4 + 0] * Jl[j * 3 + 0]
                       + MA[j * 12 + r * 4 + 1] * Jl[j * 3 + 1]
                       + MA[j * 12 + r * 4 + 2] * Jl[j * 3 + 2];
        rel_tf[(size_t)b * NJ * 16 + j * 16 + e] = aje - tj;
    } else {
        rel_tf[(size_t)b * NJ * 16 + j * 16 + e] = aje;
    }
    if (tid < NJ * 4) {
        const int j2 = tid >> 2, c2 = tid & 3;
        rel_tf[(size_t)b * NJ * 16 + j2 * 16 + 12 + c2] = (c2 == 3) ? 1.0f : 0.0f;
    }
}

// ---------------------------------------------------------------------------
// Kernel 2: vertex blend v5. 2 verts/thread. Weights straight from J-major
// transpose (coalesced float2, no W-LDS). M via b128 broadcasts amortized x2.
// Tiny LDS footprint; VGPR capped by 8-joint weight chunks.
// ---------------------------------------------------------------------------
#define L5TH 256
#define L5VPB 512

__global__ __launch_bounds__(L5TH) void lbs5(
    const float* __restrict__ verts,    // (B,V,3)
    const float* __restrict__ wT,       // (J, WT_LD)
    const float* __restrict__ rel_tf,   // (B,J,4,4)
    float* __restrict__ out_verts)      // (B,V,3)
{
    __shared__ float Ml[NJ * 16];       // 1.5 KB
    __shared__ float Vio[L5TH * 7];     // 7 KB-ish: 6 floats + 1 pad per thread
    const int b = blockIdx.y, tid = threadIdx.x;
    const int v0 = blockIdx.x * L5VPB;
    const int nvalid = min(L5VPB, NV - v0);   // 512 or 234

    for (int i = tid; i < NJ * 16; i += L5TH)
        Ml[i] = rel_tf[(size_t)b * NJ * 16 + i];

    // stage verts: nvalid*3 floats via coalesced float2 into stride-7 slots
    {
        const float2* vg = reinterpret_cast<const float2*>(verts + ((size_t)b * NV + v0) * 3);
        const int nf2 = nvalid * 3 / 2;   // even (512*3/2=768, 234*3/2=351)
        for (int i = tid; i < nf2; i += L5TH) {
            const float2 q = vg[i];
            const int f0 = 2 * i, f1 = 2 * i + 1;
            Vio[(f0 / 6) * 7 + (f0 % 6)] = q.x;
            Vio[(f1 / 6) * 7 + (f1 % 6)] = q.y;
        }
    }
    __syncthreads();

    float px[2], py[2], pz[2];
#pragma unroll
    for (int k = 0; k < 2; ++k) {       // stride-7 reads: conflict-free
        px[k] = Vio[tid * 7 + k * 3 + 0];
        py[k] = Vio[tid * 7 + k * 3 + 1];
        pz[k] = Vio[tid * 7 + k * 3 + 2];
    }

    float acc[2][12];
#pragma unroll
    for (int k = 0; k < 2; ++k)
#pragma unroll
        for (int q = 0; q < 12; ++q) acc[k][q] = 0.0f;

    const int vbase = v0 + tid * 2;     // max 7166 < WT_LD pad: tail reads in-buffer
#pragma unroll
    for (int jc = 0; jc < 3; ++jc) {    // 3 chunks x 8 joints: caps VGPR pressure
        float2 wv[8];
#pragma unroll
        for (int l = 0; l < 8; ++l) {
            const int j = jc * 8 + l;
            wv[l] = *reinterpret_cast<const float2*>(wT + (size_t)j * WT_LD + vbase);
        }
#pragma unroll
        for (int l = 0; l < 8; ++l) {
            const int j = jc * 8 + l;
            const float4 m0 = *reinterpret_cast<const float4*>(Ml + j * 16 + 0);
            const float4 m1 = *reinterpret_cast<const float4*>(Ml + j * 16 + 4);
            const float4 m2 = *reinterpret_cast<const float4*>(Ml + j * 16 + 8);
            const float m[12] = {m0.x, m0.y, m0.z, m0.w, m1.x, m1.y,
                                 m1.z, m1.w, m2.x, m2.y, m2.z, m2.w};
            const float w0 = wv[l].x, w1 = wv[l].y;
#pragma unroll
            for (int q = 0; q < 12; ++q) {
                acc[0][q] += w0 * m[q];
                acc[1][q] += w1 * m[q];
            }
        }
    }

    float o[2][3];
#pragma unroll
    for (int k = 0; k < 2; ++k)
#pragma unroll
        for (int r = 0; r < 3; ++r)
            o[k][r] = acc[k][r * 4 + 0] * px[k] + acc[k][r * 4 + 1] * py[k] +
                      acc[k][r * 4 + 2] * pz[k] + acc[k][r * 4 + 3];

    __syncthreads();   // done with Vio's input role
#pragma unroll
    for (int k = 0; k < 2; ++k)
        if (tid * 2 + k < nvalid) {
#pragma unroll
            for (int r = 0; r < 3; ++r) Vio[tid * 7 + k * 3 + r] = o[k][r];
        }
    __syncthreads();

    // coalesced float2 store
    {
        float2* og = reinterpret_cast<float2*>(out_verts + ((size_t)b * NV + v0) * 3);
        const int nf2 = nvalid * 3 / 2;
        for (int i = tid; i < nf2; i += L5TH) {
            const int f0 = 2 * i, f1 = 2 * i + 1;
            og[i] = make_float2(Vio[(f0 / 6) * 7 + (f0 % 6)],
                                Vio[(f1 / 6) * 7 + (f1 % 6)]);
        }
    }
}

extern "C" void kernel_launch(void* const* d_in, const int* in_sizes, int n_in,
                              void* d_out, int out_size, void* d_ws, size_t ws_size,
                              hipStream_t stream) {
    const float* rot     = (const float*)d_in[0];   // (B,J,3,3)
    const float* joints  = (const float*)d_in[1];   // (B,J,3)
    const float* verts   = (const float*)d_in[2];   // (B,V,3)
    const float* weights = (const float*)d_in[3];   // (V,J)

    float* out = (float*)d_out;
    float* posed_verts  = out;                                   // B*V*3
    float* posed_joints = out + (size_t)NB * NV * 3;             // B*J*3
    float* rel_tf       = posed_joints + (size_t)NB * NJ * 3;    // B*J*16
    float* wT           = (float*)d_ws;                          // 24*7168 floats = 688 KB

    transpose_w2<<<(NV + 255) / 256, 256, 0, stream>>>(weights, wT);
    chain2<<<NB, 288, 0, stream>>>(rot, joints, posed_joints, rel_tf);

    const int nbx = (NV + L5VPB - 1) / L5VPB;   // 14
    lbs5<<<dim3(nbx, NB), L5TH, 0, stream>>>(verts, wT, rel_tf, posed_verts);
}

// Round 10
// 102.621 us; speedup vs baseline: 1.4829x; 1.4829x over previous
//
#include <hip/hip_runtime.h>

#define NB 256
#define NJ 24
#define NV 6890
#define WT_LD 7168   // transposed-W row stride (floats); covers max OOB tail read

// ---------------------------------------------------------------------------
// Kernel 0: transpose weights (V,J) -> (J, WT_LD) in d_ws, coalesced both sides.
// ---------------------------------------------------------------------------
__global__ __launch_bounds__(256) void transpose_w2(const float* __restrict__ w,
                                                    float* __restrict__ wT) {
    __shared__ float Wl[256 * 25];   // row stride 25: gcd(25,32)=1
    const int v0 = blockIdx.x * 256, tid = threadIdx.x;
    const int nvalid = min(256, NV - v0);

    const float4* wg = reinterpret_cast<const float4*>(w + (size_t)v0 * NJ);
    const int nf4 = nvalid * NJ / 4;
    for (int i = tid; i < nf4; i += 256) {
        const float4 q = wg[i];
        const int f = i * 4, v = f / NJ, j = f % NJ;   // j in {0,4,...,20}
        float* d = &Wl[v * 25 + j];
        d[0] = q.x; d[1] = q.y; d[2] = q.z; d[3] = q.w;
    }
    __syncthreads();

#pragma unroll
    for (int j = 0; j < NJ; ++j)
        for (int v = tid; v < nvalid; v += 256)
            wT[(size_t)j * WT_LD + v0 + v] = Wl[v * 25 + j];   // coalesced store
}

// ---------------------------------------------------------------------------
// Kernel 1: kinematic chain via parallel ancestor doubling (unchanged, passing).
// ---------------------------------------------------------------------------
__device__ __constant__ int ANC[4][NJ] = {
  {-1, 0, 0, 0, 1, 2, 3, 4, 5, 6, 7, 8, 9, 9, 9,12,13,14,16,17,18,19,20,21},
  {-1,-1,-1,-1, 0, 0, 0, 1, 2, 3, 4, 5, 6, 6, 6, 9, 9, 9,13,14,16,17,18,19},
  {-1,-1,-1,-1,-1,-1,-1,-1,-1,-1, 0, 0, 0, 0, 0, 3, 3, 3, 6, 6, 9, 9,13,14},
  {-1,-1,-1,-1,-1,-1,-1,-1,-1,-1,-1,-1,-1,-1,-1,-1,-1,-1,-1,-1,-1,-1, 0, 0}};

__global__ __launch_bounds__(288) void chain2(
    const float* __restrict__ rot,      // (B,J,3,3)
    const float* __restrict__ joints,   // (B,J,3)
    float* __restrict__ posed_joints,   // (B,J,3)
    float* __restrict__ rel_tf)         // (B,J,4,4)
{
    __shared__ float Jl[NJ * 3];
    __shared__ float MA[NJ * 12];
    __shared__ float MB[NJ * 12];
    const int b = blockIdx.x, tid = threadIdx.x;
    const int j = tid / 12, e = tid % 12, r = e >> 2, c = e & 3;
    constexpr int par[NJ] = {0,0,0,0,1,2,3,4,5,6,7,8,9,9,9,12,13,14,16,17,18,19,20,21};

    if (tid < NJ * 3) Jl[tid] = joints[(size_t)b * NJ * 3 + tid];
    __syncthreads();

    float tv;
    if (c < 3) {
        tv = rot[(size_t)b * NJ * 9 + j * 9 + r * 3 + c];
    } else {
        tv = Jl[j * 3 + r];
        if (j > 0) tv -= Jl[par[j] * 3 + r];
    }
    MA[j * 12 + e] = tv;
    __syncthreads();

#define DSTEP(SRC, DST, K)                                                 \
    do {                                                                   \
        const int a = ANC[K][j];                                           \
        float nv;                                                          \
        if (a < 0) {                                                       \
            nv = SRC[j * 12 + e];                                          \
        } else {                                                           \
            nv = SRC[a * 12 + r * 4 + 0] * SRC[j * 12 + 0 + c]            \
               + SRC[a * 12 + r * 4 + 1] * SRC[j * 12 + 4 + c]            \
               + SRC[a * 12 + r * 4 + 2] * SRC[j * 12 + 8 + c];           \
            if (c == 3) nv += SRC[a * 12 + r * 4 + 3];                    \
        }                                                                  \
        DST[j * 12 + e] = nv;                                              \
        __syncthreads();                                                   \
    } while (0)

    DSTEP(MA, MB, 0);
    DSTEP(MB, MA, 1);
    DSTEP(MA, MB, 2);
    DSTEP(MB, MA, 3);

    const float aje = MA[j * 12 + e];
    if (c == 3) {
        posed_joints[(size_t)b * NJ * 3 + j * 3 + r] = aje;
        const float tj = MA[j * 12 + r * 4 + 0] * Jl[j * 3 + 0]
                       + MA[j * 12 + r * 4 + 1] * Jl[j * 3 + 1]
                       + MA[j * 12 + r * 4 + 2] * Jl[j * 3 + 2];
        rel_tf[(size_t)b * NJ * 16 + j * 16 + e] = aje - tj;
    } else {
        rel_tf[(size_t)b * NJ * 16 + j * 16 + e] = aje;
    }
    if (tid < NJ * 4) {
        const int j2 = tid >> 2, c2 = tid & 3;
        rel_tf[(size_t)b * NJ * 16 + j2 * 16 + 12 + c2] = (c2 == 3) ? 1.0f : 0.0f;
    }
}

// ---------------------------------------------------------------------------
// Kernel 2: vertex blend v6. 1 vertex/thread (low VGPR). Weights: J-major
// transpose, coalesced b32. M: wave-uniform GLOBAL loads (no LDS pipe, no
// lane amplification), chunked 4 joints with unroll-1 to stop load hoisting.
// LDS only for coalesced vert/out staging (~12 LDS ops/thread).
// ---------------------------------------------------------------------------
__global__ __launch_bounds__(256) void lbs6(
    const float* __restrict__ verts,    // (B,V,3)
    const float* __restrict__ wT,       // (J, WT_LD)
    const float* __restrict__ rel_tf,   // (B,J,4,4)
    float* __restrict__ out_verts)      // (B,V,3)
{
    __shared__ float Vio[256 * 3];      // 3 KB: verts in, outputs out
    const int b = blockIdx.y, tid = threadIdx.x;
    const int v0 = blockIdx.x * 256;
    const int nvalid = min(256, NV - v0);       // 256 or 234
    const float* __restrict__ Mb = rel_tf + (size_t)b * NJ * 16;  // uniform

    // stage verts: coalesced float2 (base even, count even)
    {
        const float2* vg = reinterpret_cast<const float2*>(verts + ((size_t)b * NV + v0) * 3);
        const int nf2 = nvalid * 3 / 2;
        for (int i = tid; i < nf2; i += 256) {
            const float2 q = vg[i];
            Vio[2 * i + 0] = q.x;
            Vio[2 * i + 1] = q.y;
        }
    }
    __syncthreads();

    // Unconditional compute: tail threads read in-bounds wT pad / stale LDS,
    // produce garbage that is never stored. Keeps M loads in uniform CF.
    const float x = Vio[tid * 3 + 0];   // stride-3: 2 lanes/bank, free
    const float y = Vio[tid * 3 + 1];
    const float z = Vio[tid * 3 + 2];
    const int v = v0 + tid;             // max 6911 < WT_LD: always in-buffer

    float acc[12];
#pragma unroll
    for (int q = 0; q < 12; ++q) acc[q] = 0.0f;

#pragma unroll 1                        // DO NOT unroll: caps live registers
    for (int jc = 0; jc < 6; ++jc) {
        float w[4];
#pragma unroll
        for (int l = 0; l < 4; ++l)
            w[l] = wT[(size_t)(jc * 4 + l) * WT_LD + v];   // coalesced b32
#pragma unroll
        for (int l = 0; l < 4; ++l) {
            const int j = jc * 4 + l;
            const float4 m0 = *reinterpret_cast<const float4*>(Mb + j * 16 + 0);
            const float4 m1 = *reinterpret_cast<const float4*>(Mb + j * 16 + 4);
            const float4 m2 = *reinterpret_cast<const float4*>(Mb + j * 16 + 8);
            const float wl = w[l];
            acc[0] += wl * m0.x; acc[1]  += wl * m0.y; acc[2]  += wl * m0.z; acc[3]  += wl * m0.w;
            acc[4] += wl * m1.x; acc[5]  += wl * m1.y; acc[6]  += wl * m1.z; acc[7]  += wl * m1.w;
            acc[8] += wl * m2.x; acc[9]  += wl * m2.y; acc[10] += wl * m2.z; acc[11] += wl * m2.w;
        }
    }

    const float o0 = acc[0] * x + acc[1] * y + acc[2]  * z + acc[3];
    const float o1 = acc[4] * x + acc[5] * y + acc[6]  * z + acc[7];
    const float o2 = acc[8] * x + acc[9] * y + acc[10] * z + acc[11];

    __syncthreads();                    // Vio input role done
    if (tid < nvalid) {
        Vio[tid * 3 + 0] = o0;
        Vio[tid * 3 + 1] = o1;
        Vio[tid * 3 + 2] = o2;
    }
    __syncthreads();

    // coalesced float2 store
    {
        float2* og = reinterpret_cast<float2*>(out_verts + ((size_t)b * NV + v0) * 3);
        const int nf2 = nvalid * 3 / 2;
        for (int i = tid; i < nf2; i += 256)
            og[i] = make_float2(Vio[2 * i + 0], Vio[2 * i + 1]);
    }
}

extern "C" void kernel_launch(void* const* d_in, const int* in_sizes, int n_in,
                              void* d_out, int out_size, void* d_ws, size_t ws_size,
                              hipStream_t stream) {
    const float* rot     = (const float*)d_in[0];   // (B,J,3,3)
    const float* joints  = (const float*)d_in[1];   // (B,J,3)
    const float* verts   = (const float*)d_in[2];   // (B,V,3)
    const float* weights = (const float*)d_in[3];   // (V,J)

    float* out = (float*)d_out;
    float* posed_verts  = out;                                   // B*V*3
    float* posed_joints = out + (size_t)NB * NV * 3;             // B*J*3
    float* rel_tf       = posed_joints + (size_t)NB * NJ * 3;    // B*J*16
    float* wT           = (float*)d_ws;                          // 24*7168 floats = 688 KB

    transpose_w2<<<(NV + 255) / 256, 256, 0, stream>>>(weights, wT);
    chain2<<<NB, 288, 0, stream>>>(rot, joints, posed_joints, rel_tf);

    const int nbx = (NV + 255) / 256;   // 27
    lbs6<<<dim3(nbx, NB), 256, 0, stream>>>(verts, wT, rel_tf, posed_verts);
}

// Round 11
// 99.993 us; speedup vs baseline: 1.5219x; 1.0263x over previous
//
#include <hip/hip_runtime.h>

#define NB 256
#define NJ 24
#define NV 6890
#define WT_LD 7168   // transposed-W row stride (floats); covers max OOB tail read

// ---------------------------------------------------------------------------
// Kernel 0: transpose weights (V,J) -> (J, WT_LD) in d_ws, coalesced both sides.
// ---------------------------------------------------------------------------
__global__ __launch_bounds__(256) void transpose_w2(const float* __restrict__ w,
                                                    float* __restrict__ wT) {
    __shared__ float Wl[256 * 25];   // row stride 25: gcd(25,32)=1
    const int v0 = blockIdx.x * 256, tid = threadIdx.x;
    const int nvalid = min(256, NV - v0);

    const float4* wg = reinterpret_cast<const float4*>(w + (size_t)v0 * NJ);
    const int nf4 = nvalid * NJ / 4;
    for (int i = tid; i < nf4; i += 256) {
        const float4 q = wg[i];
        const int f = i * 4, v = f / NJ, j = f % NJ;   // j in {0,4,...,20}
        float* d = &Wl[v * 25 + j];
        d[0] = q.x; d[1] = q.y; d[2] = q.z; d[3] = q.w;
    }
    __syncthreads();

#pragma unroll
    for (int j = 0; j < NJ; ++j)
        for (int v = tid; v < nvalid; v += 256)
            wT[(size_t)j * WT_LD + v0 + v] = Wl[v * 25 + j];   // coalesced store
}

// ---------------------------------------------------------------------------
// Kernel 1: kinematic chain via parallel ancestor doubling (unchanged, passing).
// ---------------------------------------------------------------------------
__device__ __constant__ int ANC[4][NJ] = {
  {-1, 0, 0, 0, 1, 2, 3, 4, 5, 6, 7, 8, 9, 9, 9,12,13,14,16,17,18,19,20,21},
  {-1,-1,-1,-1, 0, 0, 0, 1, 2, 3, 4, 5, 6, 6, 6, 9, 9, 9,13,14,16,17,18,19},
  {-1,-1,-1,-1,-1,-1,-1,-1,-1,-1, 0, 0, 0, 0, 0, 3, 3, 3, 6, 6, 9, 9,13,14},
  {-1,-1,-1,-1,-1,-1,-1,-1,-1,-1,-1,-1,-1,-1,-1,-1,-1,-1,-1,-1,-1,-1, 0, 0}};

__global__ __launch_bounds__(288) void chain2(
    const float* __restrict__ rot,      // (B,J,3,3)
    const float* __restrict__ joints,   // (B,J,3)
    float* __restrict__ posed_joints,   // (B,J,3)
    float* __restrict__ rel_tf)         // (B,J,4,4)
{
    __shared__ float Jl[NJ * 3];
    __shared__ float MA[NJ * 12];
    __shared__ float MB[NJ * 12];
    const int b = blockIdx.x, tid = threadIdx.x;
    const int j = tid / 12, e = tid % 12, r = e >> 2, c = e & 3;
    constexpr int par[NJ] = {0,0,0,0,1,2,3,4,5,6,7,8,9,9,9,12,13,14,16,17,18,19,20,21};

    if (tid < NJ * 3) Jl[tid] = joints[(size_t)b * NJ * 3 + tid];
    __syncthreads();

    float tv;
    if (c < 3) {
        tv = rot[(size_t)b * NJ * 9 + j * 9 + r * 3 + c];
    } else {
        tv = Jl[j * 3 + r];
        if (j > 0) tv -= Jl[par[j] * 3 + r];
    }
    MA[j * 12 + e] = tv;
    __syncthreads();

#define DSTEP(SRC, DST, K)                                                 \
    do {                                                                   \
        const int a = ANC[K][j];                                           \
        float nv;                                                          \
        if (a < 0) {                                                       \
            nv = SRC[j * 12 + e];                                          \
        } else {                                                           \
            nv = SRC[a * 12 + r * 4 + 0] * SRC[j * 12 + 0 + c]            \
               + SRC[a * 12 + r * 4 + 1] * SRC[j * 12 + 4 + c]            \
               + SRC[a * 12 + r * 4 + 2] * SRC[j * 12 + 8 + c];           \
            if (c == 3) nv += SRC[a * 12 + r * 4 + 3];                    \
        }                                                                  \
        DST[j * 12 + e] = nv;                                              \
        __syncthreads();                                                   \
    } while (0)

    DSTEP(MA, MB, 0);
    DSTEP(MB, MA, 1);
    DSTEP(MA, MB, 2);
    DSTEP(MB, MA, 3);

    const float aje = MA[j * 12 + e];
    if (c == 3) {
        posed_joints[(size_t)b * NJ * 3 + j * 3 + r] = aje;
        const float tj = MA[j * 12 + r * 4 + 0] * Jl[j * 3 + 0]
                       + MA[j * 12 + r * 4 + 1] * Jl[j * 3 + 1]
                       + MA[j * 12 + r * 4 + 2] * Jl[j * 3 + 2];
        rel_tf[(size_t)b * NJ * 16 + j * 16 + e] = aje - tj;
    } else {
        rel_tf[(size_t)b * NJ * 16 + j * 16 + e] = aje;
    }
    if (tid < NJ * 4) {
        const int j2 = tid >> 2, c2 = tid & 3;
        rel_tf[(size_t)b * NJ * 16 + j2 * 16 + 12 + c2] = (c2 == 3) ? 1.0f : 0.0f;
    }
}

// ---------------------------------------------------------------------------
// Kernel 2: vertex blend v7 = v6 structure + 2 verts/thread.
// Weights: J-major transpose, coalesced float2. M: wave-uniform GLOBAL loads.
// jc-chunked (4 joints) with unroll-1 to stop load hoisting (lbs5 lesson:
// full unroll -> VGPR 192; lbs6's unroll 1 -> fast).
// LDS only for coalesced vert/out staging (stride-7 slots, conflict-free).
// ---------------------------------------------------------------------------
#define L7TH 256
#define L7VPB 512

__global__ __launch_bounds__(L7TH) void lbs7(
    const float* __restrict__ verts,    // (B,V,3)
    const float* __restrict__ wT,       // (J, WT_LD)
    const float* __restrict__ rel_tf,   // (B,J,4,4)
    float* __restrict__ out_verts)      // (B,V,3)
{
    __shared__ float Vio[L7TH * 7];     // 7 KB: 6 floats + 1 pad per thread
    const int b = blockIdx.y, tid = threadIdx.x;
    const int v0 = blockIdx.x * L7VPB;
    const int nvalid = min(L7VPB, NV - v0);     // 512 or 234
    const float* __restrict__ Mb = rel_tf + (size_t)b * NJ * 16;  // uniform

    // stage verts: coalesced float2 into stride-7 slots
    {
        const float2* vg = reinterpret_cast<const float2*>(verts + ((size_t)b * NV + v0) * 3);
        const int nf2 = nvalid * 3 / 2;         // 768 or 351
        for (int i = tid; i < nf2; i += L7TH) {
            const float2 q = vg[i];
            const int f0 = 2 * i, f1 = 2 * i + 1;
            Vio[(f0 / 6) * 7 + (f0 % 6)] = q.x;
            Vio[(f1 / 6) * 7 + (f1 % 6)] = q.y;
        }
    }
    __syncthreads();

    // Unconditional compute: tail threads read wT pad / stale LDS, results
    // discarded at the masked write-back. Keeps M loads in uniform CF.
    float px[2], py[2], pz[2];
#pragma unroll
    for (int k = 0; k < 2; ++k) {       // stride-7: conflict-free
        px[k] = Vio[tid * 7 + k * 3 + 0];
        py[k] = Vio[tid * 7 + k * 3 + 1];
        pz[k] = Vio[tid * 7 + k * 3 + 2];
    }
    const int vbase = v0 + tid * 2;     // max 7166+1 < WT_LD: in-buffer

    float acc[2][12];
#pragma unroll
    for (int k = 0; k < 2; ++k)
#pragma unroll
        for (int q = 0; q < 12; ++q) acc[k][q] = 0.0f;

#pragma unroll 1                        // DO NOT unroll: caps live registers
    for (int jc = 0; jc < 6; ++jc) {
        float2 w[4];
#pragma unroll
        for (int l = 0; l < 4; ++l)
            w[l] = *reinterpret_cast<const float2*>(wT + (size_t)(jc * 4 + l) * WT_LD + vbase);
#pragma unroll
        for (int l = 0; l < 4; ++l) {
            const int j = jc * 4 + l;
            const float4 m0 = *reinterpret_cast<const float4*>(Mb + j * 16 + 0);
            const float4 m1 = *reinterpret_cast<const float4*>(Mb + j * 16 + 4);
            const float4 m2 = *reinterpret_cast<const float4*>(Mb + j * 16 + 8);
            const float w0 = w[l].x, w1 = w[l].y;
            acc[0][0] += w0 * m0.x; acc[0][1]  += w0 * m0.y; acc[0][2]  += w0 * m0.z; acc[0][3]  += w0 * m0.w;
            acc[0][4] += w0 * m1.x; acc[0][5]  += w0 * m1.y; acc[0][6]  += w0 * m1.z; acc[0][7]  += w0 * m1.w;
            acc[0][8] += w0 * m2.x; acc[0][9]  += w0 * m2.y; acc[0][10] += w0 * m2.z; acc[0][11] += w0 * m2.w;
            acc[1][0] += w1 * m0.x; acc[1][1]  += w1 * m0.y; acc[1][2]  += w1 * m0.z; acc[1][3]  += w1 * m0.w;
            acc[1][4] += w1 * m1.x; acc[1][5]  += w1 * m1.y; acc[1][6]  += w1 * m1.z; acc[1][7]  += w1 * m1.w;
            acc[1][8] += w1 * m2.x; acc[1][9]  += w1 * m2.y; acc[1][10] += w1 * m2.z; acc[1][11] += w1 * m2.w;
        }
    }

    float o[2][3];
#pragma unroll
    for (int k = 0; k < 2; ++k)
#pragma unroll
        for (int r = 0; r < 3; ++r)
            o[k][r] = acc[k][r * 4 + 0] * px[k] + acc[k][r * 4 + 1] * py[k] +
                      acc[k][r * 4 + 2] * pz[k] + acc[k][r * 4 + 3];

    __syncthreads();                    // Vio input role done
#pragma unroll
    for (int k = 0; k < 2; ++k)
        if (tid * 2 + k < nvalid) {
#pragma unroll
            for (int r = 0; r < 3; ++r) Vio[tid * 7 + k * 3 + r] = o[k][r];
        }
    __syncthreads();

    // coalesced float2 store from stride-7 slots
    {
        float2* og = reinterpret_cast<float2*>(out_verts + ((size_t)b * NV + v0) * 3);
        const int nf2 = nvalid * 3 / 2;
        for (int i = tid; i < nf2; i += L7TH) {
            const int f0 = 2 * i, f1 = 2 * i + 1;
            og[i] = make_float2(Vio[(f0 / 6) * 7 + (f0 % 6)],
                                Vio[(f1 / 6) * 7 + (f1 % 6)]);
        }
    }
}

extern "C" void kernel_launch(void* const* d_in, const int* in_sizes, int n_in,
                              void* d_out, int out_size, void* d_ws, size_t ws_size,
                              hipStream_t stream) {
    const float* rot     = (const float*)d_in[0];   // (B,J,3,3)
    const float* joints  = (const float*)d_in[1];   // (B,J,3)
    const float* verts   = (const float*)d_in[2];   // (B,V,3)
    const float* weights = (const float*)d_in[3];   // (V,J)

    float* out = (float*)d_out;
    float* posed_verts  = out;                                   // B*V*3
    float* posed_joints = out + (size_t)NB * NV * 3;             // B*J*3
    float* rel_tf       = posed_joints + (size_t)NB * NJ * 3;    // B*J*16
    float* wT           = (float*)d_ws;                          // 24*7168 floats = 688 KB

    transpose_w2<<<(NV + 255) / 256, 256, 0, stream>>>(weights, wT);
    chain2<<<NB, 288, 0, stream>>>(rot, joints, posed_joints, rel_tf);

    const int nbx = (NV + L7VPB - 1) / L7VPB;   // 14
    lbs7<<<dim3(nbx, NB), L7TH, 0, stream>>>(verts, wT, rel_tf, posed_verts);
}